// Round 3
// baseline (507.658 us; speedup 1.0000x reference)
//
#include <hip/hip_runtime.h>

// Attn_Pred_Model: 8-tap decayed shift-sum along S + biases, masked.
// x: [16,16,4096,64] fp32. Analytic mask/arange2, masked-strip skip,
// chunked register loads, plain stores, plane-fastest block decode.
//
// Round 3 change — MIRROR-PAIRED STRIPS for static load balance:
// row s has q(s)=s>>6 active buckets; row 4095-s has 63-q(s). Each wave
// now owns 2 strips from the top half and 2 mirrored strips from the
// bottom half (strip st: even -> top chunk, odd -> bottom chunk), so
// every wave in the grid carries ~2*63 active bucket-rows. Previously
// work per block ranged ~0..64 buckets/row and the exactly-resident
// grid (no backfill) drained to a low-occupancy heavy tail
// (OccupancyPercent 56%, busy-time BW 4.2 TB/s vs delivered 2.37).
//
// Analytic identities (S=4096, BUCKET=64, BUCKETS_MIN=2):
//   arange2[s,j] = ((s>>6) - j) & 63
//   mask[s,j]    = (s >= 128) && (j < s>>6)
// q = s>>6 is strip-constant (strips are 32 rows, 32-aligned).

#define S_DIM 4096
#define PAST 8
#define RROWS 32                      // rows per thread
#define CHUNK 8                       // rows per load batch (= PAST)
#define STRIPS 16                     // strips per 256-thread block
#define CHUNK_ROWS 256                // rows per (block, half): 8 strips * 32
#define BLOCKS_PER_PLANE 8
#define PLANES 256                    // 16*16

typedef float v4f __attribute__((ext_vector_type(4)));

// Compute+store CHUNK rows. W = previous 8 rows (window), C = this chunk's
// 8 rows. Row d of the chunk needs C[0..d-1] and W[d..7]; all indices are
// compile-time after unroll, so A/B stay in registers (no scratch).
#define DO_CHUNK(W, C, rbase)                                               \
    {                                                                       \
        _Pragma("unroll")                                                   \
        for (int d = 0; d < CHUNK; ++d) {                                   \
            v4f acc = c[0] * ((d - 1 >= 0) ? C[d - 1] : W[CHUNK + d - 1]);  \
            _Pragma("unroll")                                               \
            for (int i = 1; i < PAST; ++i) {                                \
                const int idx = d - 1 - i;                                  \
                acc += c[i] * ((idx >= 0) ? C[idx] : W[CHUNK + idx]);       \
            }                                                               \
            op[((rbase) + d) * 16 + j4] = (acc + bias) * mk;                \
        }                                                                   \
    }

__global__ __launch_bounds__(256) void attn_pred_kernel(
    const float* __restrict__ x,
    const float* __restrict__ pb_fwd,
    const float* __restrict__ pb_bwd,
    const float* __restrict__ alpha_p,
    const float* __restrict__ beta_p,
    float* __restrict__ out)
{
    const int j4 = threadIdx.x & 15;          // which float4 along B
    const int st = threadIdx.x >> 4;          // strip within block [0,16)
    const int bh = blockIdx.x & (PLANES - 1); // plane: FASTEST-varying
    const int b  = blockIdx.x >> 8;           // block slot within plane [0,8)

    // Mirror pairing: even strips -> top chunk [256b, 256b+256),
    // odd strips -> bottom chunk [4096-256(b+1), 4096-256b).
    const int pair = st >> 1;                 // [0,8)
    const int odd  = st & 1;
    const int s0 = odd ? (S_DIM - CHUNK_ROWS * (b + 1) + RROWS * pair)
                       : (CHUNK_ROWS * b + RROWS * pair);

    const int q  = s0 >> 6;                   // strip-constant bucket row
    const int jb = j4 << 2;                   // first j of this thread's float4

    const size_t plane = (size_t)bh * (S_DIM * 16);   // in v4f units
    const v4f* __restrict__ xp = (const v4f*)x + plane;
    v4f* __restrict__       op = (v4f*)out + plane;

    // Fully-masked strip: write zeros, skip all loads.
    if (s0 < 128 || jb >= q) {
        const v4f z = (v4f){0.f, 0.f, 0.f, 0.f};
        #pragma unroll
        for (int r = 0; r < RROWS; ++r)
            op[(s0 + r) * 16 + j4] = z;
        return;
    }

    // s0 >= 128 here, so the window preload needs no s<0 guard.
    const float alpha = alpha_p[0];
    const float beta  = beta_p[0];
    float c[PAST];
    c[0] = alpha;
    #pragma unroll
    for (int i = 1; i < PAST; ++i) c[i] = c[i - 1] * beta;

    const v4f bf = ((const v4f*)pb_fwd)[j4];
    v4f bias;
    bias.x = bf.x + pb_bwd[(q - jb    ) & 63];
    bias.y = bf.y + pb_bwd[(q - jb - 1) & 63];
    bias.z = bf.z + pb_bwd[(q - jb - 2) & 63];
    bias.w = bf.w + pb_bwd[(q - jb - 3) & 63];

    v4f mk;
    mk.x = 1.f;                               // jb < q guaranteed here
    mk.y = (jb + 1 < q) ? 1.f : 0.f;
    mk.z = (jb + 2 < q) ? 1.f : 0.f;
    mk.w = (jb + 3 < q) ? 1.f : 0.f;

    // Chunked loads: 8 independent row-loads issued back-to-back per batch.
    v4f A[CHUNK], B[CHUNK];

    #pragma unroll
    for (int k = 0; k < CHUNK; ++k)           // window: rows s0-8..s0-1
        A[k] = xp[(s0 - PAST + k) * 16 + j4];

    #pragma unroll
    for (int k = 0; k < CHUNK; ++k)           // chunk 0: rows s0..s0+7
        B[k] = xp[(s0 + k) * 16 + j4];
    DO_CHUNK(A, B, s0)

    #pragma unroll
    for (int k = 0; k < CHUNK; ++k)           // chunk 1
        A[k] = xp[(s0 + CHUNK + k) * 16 + j4];
    DO_CHUNK(B, A, s0 + CHUNK)

    #pragma unroll
    for (int k = 0; k < CHUNK; ++k)           // chunk 2
        B[k] = xp[(s0 + 2 * CHUNK + k) * 16 + j4];
    DO_CHUNK(A, B, s0 + 2 * CHUNK)

    #pragma unroll
    for (int k = 0; k < CHUNK; ++k)           // chunk 3
        A[k] = xp[(s0 + 3 * CHUNK + k) * 16 + j4];
    DO_CHUNK(B, A, s0 + 3 * CHUNK)
}

extern "C" void kernel_launch(void* const* d_in, const int* in_sizes, int n_in,
                              void* d_out, int out_size, void* d_ws, size_t ws_size,
                              hipStream_t stream) {
    const float* x       = (const float*)d_in[0];
    const float* pb_fwd  = (const float*)d_in[1];
    const float* pb_bwd  = (const float*)d_in[2];
    const float* alpha_p = (const float*)d_in[3];
    const float* beta_p  = (const float*)d_in[4];
    // d_in[5] = arange2 (int64), d_in[6] = mask -- both computed analytically
    float* out = (float*)d_out;

    const int grid = PLANES * BLOCKS_PER_PLANE;  // 2048 blocks x 256 threads
    attn_pred_kernel<<<grid, 256, 0, stream>>>(x, pb_fwd, pb_bwd, alpha_p,
                                               beta_p, out);
}